// Round 16
// baseline (301.818 us; speedup 1.0000x reference)
//
#include <hip/hip_runtime.h>

#define NB 8
#define IC 64
#define OC 64
#define HH 256
#define WD 512
#define PP 258 // padded pitch

typedef __bf16 bf16x8 __attribute__((ext_vector_type(8)));
typedef float f32x16 __attribute__((ext_vector_type(16)));
typedef float f32x2 __attribute__((ext_vector_type(2)));

// Weight math: modulate, demodulate, compose with blur into E[6][6].
__device__ inline void compute_E(const float* __restrict__ w_conv, float stv,
                                 int oc, float E[6][6]) {
  const float coef_conv = 1.0f / 24.0f; // 1/sqrt(3*3*64)
  const float s = stv * coef_conv;
  const int ic = threadIdx.x & 63;

  float wm[3][3];
  float ssq = 0.f;
  #pragma unroll
  for (int kh = 0; kh < 3; ++kh)
    #pragma unroll
    for (int kw = 0; kw < 3; ++kw) {
      float v = w_conv[((kh * 3 + kw) * IC + ic) * OC + oc] * s;
      wm[kh][kw] = v;
      ssq += v * v;
    }
  #pragma unroll
  for (int off = 32; off > 0; off >>= 1) ssq += __shfl_xor(ssq, off);
  const float d = rsqrtf(ssq + 1e-8f);
  #pragma unroll
  for (int kh = 0; kh < 3; ++kh)
    #pragma unroll
    for (int kw = 0; kw < 3; ++kw) wm[kh][kw] *= d;

  const float g[4] = {0.25f, 0.75f, 0.75f, 0.25f};
  #pragma unroll
  for (int a = 0; a < 6; ++a)
    #pragma unroll
    for (int c = 0; c < 6; ++c) {
      float acc = 0.f;
      #pragma unroll
      for (int dh = 0; dh < 3; ++dh) {
        int u = a - dh;
        if (u < 0 || u > 3) continue;
        #pragma unroll
        for (int dw = 0; dw < 3; ++dw) {
          int v = c - dw;
          if (v < 0 || v > 3) continue;
          acc = fmaf(wm[dh][dw], g[u] * g[v], acc);
        }
      }
      E[a][c] = acc;
    }
}

__device__ inline float style_of(const float* __restrict__ w,
                                 const float* __restrict__ w_dense,
                                 const float* __restrict__ b_mod, int b,
                                 int ic) {
  const float coef_dense = 0.044194173824159216f; // 1/sqrt(512)
  const float* wr = w + b * WD;
  float acc = 0.f;
  for (int k = 0; k < WD; ++k) acc = fmaf(wr[k], w_dense[k * IC + ic], acc);
  return acc * coef_dense + b_mod[ic] + 1.0f;
}

// ---- fused pre-pass: xtp role (bid<2056) + pwfs role (bid>=2056) ----
// xtp: x [b][ic][m][n] f32 -> padded xTg [b][258][258][ic] bf16 (+guard)
// pwfs: PWf frag idx = ph*72 + tap*8 + ocg*4 + ks; 64 lanes x 16B each.
#define XS 268 // u16 LDS stride
__global__ __launch_bounds__(256) void pre_kernel(
    const float* __restrict__ x, const float* __restrict__ w,
    const float* __restrict__ w_dense, const float* __restrict__ b_mod,
    const float* __restrict__ w_conv, __bf16* __restrict__ xTg,
    __bf16* __restrict__ PWf) {
  __shared__ unsigned short buf[64 * XS];
  const int tid = threadIdx.x;
  const int bid = blockIdx.x;

  if (bid >= 2056) {
    // ---- pwfs role: 128 blocks, 4 waves each = one oc per wave ----
    const int bid2 = bid - 2056;
    const int b = bid2 >> 4;
    const int ocq = bid2 & 15;
    const int oc = ocq * 4 + (tid >> 6);
    const int ic = tid & 63;

    float stv = style_of(w, w_dense, b_mod, b, ic);
    float E[6][6];
    compute_E(w_conv, stv, oc, E);

    const int ks = ic >> 4;
    const int h = (ic >> 3) & 1;
    const int e = ic & 7;
    const int lane = (oc & 31) + 32 * h;
    const int ocg = oc >> 5;

    #pragma unroll
    for (int pp = 0; pp < 2; ++pp)
      #pragma unroll
      for (int pq = 0; pq < 2; ++pq) {
        const int ph = pp * 2 + pq;
        #pragma unroll
        for (int j = 0; j < 3; ++j)
          #pragma unroll
          for (int l = 0; l < 3; ++l) {
            const int tap = j * 3 + l;
            float val = E[2 * j + 1 - pp][2 * l + 1 - pq];
            size_t off =
                ((size_t)(((((b * 4 + ph) * 9 + tap) * 2 + ocg) * 4 + ks)) *
                     64 + lane) * 8 + e;
            PWf[off] = (__bf16)val;
          }
      }
    return;
  }

  // ---- xtp role ----
  const int m = bid % 257; // 0..256 ; 256 = guard-zero pass
  const int b = bid / 257;

  if (m == 256) {
    uint4 z = make_uint4(0, 0, 0, 0);
    for (int i = tid; i < 8224; i += 256) {
      int pix = i >> 3;
      int sub = i & 7;
      int pr, pc;
      if (pix < 258) {
        pr = 0; pc = pix;
      } else if (pix < 516) {
        pr = 257; pc = pix - 258;
      } else {
        int rem = pix - 516; // 0..511
        pr = 1 + (rem >> 1);
        pc = (rem & 1) ? 257 : 0;
      }
      *(uint4*)(xTg + ((size_t)(b * PP + pr) * PP + pc) * 64 + sub * 8) = z;
    }
    return;
  }

  const int ln = tid & 63, grp = tid >> 6;
  #pragma unroll
  for (int p = 0; p < 16; ++p) {
    const int ic = p * 4 + grp;
    float4 v = *(const float4*)(x + ((size_t)(b * 64 + ic) * 256 + m) * 256 +
                                ln * 4);
    ushort4 u4;
    u4.x = __builtin_bit_cast(unsigned short, (__bf16)v.x);
    u4.y = __builtin_bit_cast(unsigned short, (__bf16)v.y);
    u4.z = __builtin_bit_cast(unsigned short, (__bf16)v.z);
    u4.w = __builtin_bit_cast(unsigned short, (__bf16)v.w);
    *(ushort4*)&buf[ic * XS + ln * 4] = u4;
  }
  __syncthreads();
  #pragma unroll
  for (int it = 0; it < 8; ++it) {
    int pix = it * 32 + (tid >> 3);
    int g = tid & 7;
    bf16x8 o;
    #pragma unroll
    for (int e = 0; e < 8; ++e)
      o[e] = __builtin_bit_cast(__bf16, buf[(g * 8 + e) * XS + pix]);
    *(bf16x8*)(xTg + ((size_t)(b * PP + m + 1) * PP + (pix + 1)) * 64 +
               g * 8) = o;
  }
}

// ---- streaming MFMA conv, 2 blocks/CU (R7 structure + XCD swizzle) ----
#define CMT 8
#define XR 10 // CMT+2
#define XC 34 // cols (pixels), storage stride

__device__ __forceinline__ void loadA(const bf16x8* __restrict__ Av, int phb,
                                      int ocg, int ks, int l, int lane,
                                      bf16x8 A[3][2]) {
  #pragma unroll
  for (int j = 0; j < 3; ++j) {
    const int tap = j * 3 + l;
    #pragma unroll
    for (int pq = 0; pq < 2; ++pq)
      A[j][pq] =
          Av[(size_t)((((phb + pq) * 9 + tap) * 2 + ocg) * 4 + ks) * 64 + lane];
  }
}

#define GLD_LDS(src, dst)                                                \
  __builtin_amdgcn_global_load_lds(                                      \
      (const __attribute__((address_space(1))) void*)(src),              \
      (__attribute__((address_space(3))) void*)(dst), 16, 0, 0)

// stage one 10x34 tile (rows split across 8 waves) via global_load_lds.
// LDS linear; source granule pre-swizzled: slot s at pixel col holds
// granule s ^ (col&7), matching the reader's XOR.
__device__ __forceinline__ void stage_tile(const __bf16* __restrict__ xTg,
                                           int b, int m0, int n0,
                                           __bf16* xsbuf, int wv, int lane) {
  const int r0 = (XR * wv) >> 3;
  const int r1 = (XR * (wv + 1)) >> 3;
  for (int row = r0; row < r1; ++row) {
    const size_t srow = (size_t)(b * PP + m0 + row) * PP;
    __bf16* ldsrow = xsbuf + row * (XC * 64);
    #pragma unroll
    for (int q = 0; q < 4; ++q) {
      int pix = q * 8 + (lane >> 3);
      int g = (lane & 7) ^ (pix & 7);
      const __bf16* src = xTg + (srow + (n0 + pix)) * 64 + g * 8;
      GLD_LDS(src, ldsrow + q * 512);
    }
    if (lane < 16) {
      int pix = 32 + (lane >> 3);
      int g = (lane & 7) ^ (pix & 7);
      const __bf16* src = xTg + (srow + (n0 + pix)) * 64 + g * 8;
      GLD_LDS(src, ldsrow + 2048);
    }
  }
}

__global__ __launch_bounds__(512, 4) void conv32s_kernel(
    const __bf16* __restrict__ xTg, const __bf16* __restrict__ PWf,
    float* __restrict__ out) {
  __shared__ __bf16 xs[XR * XC * 64]; // 43520 B single buffer

  const int tid = threadIdx.x;
  const int lane = tid & 63;
  const int wv = tid >> 6; // 0..7
  const int pp = wv & 1;
  const int rh = wv >> 1; // 0..3, 2 rows each

  // XCD swizzle: each XCD owns one b (64 consecutive bids)
  const int raw = blockIdx.x; // 512 = 8b * 2ocg * 32mt
  const int bid = (raw & 7) * 64 + (raw >> 3);
  const int mtile = bid & 31;
  const int ocg = (bid >> 5) & 1;
  const int b = bid >> 6;
  const int m0 = mtile * CMT;

  const int ln31 = lane & 31;
  const int lh = lane >> 5;
  const bf16x8* Av = (const bf16x8*)PWf;
  const int phb = b * 4 + pp * 2;

  stage_tile(xTg, b, m0, 0, xs, wv, lane);
  __syncthreads();

  #pragma unroll 1
  for (int t = 0; t < 8; ++t) {
    const int n0 = t * 32;

    f32x16 acc[2][2]; // [mw][pq]
    #pragma unroll
    for (int mw = 0; mw < 2; ++mw)
      #pragma unroll
      for (int pq = 0; pq < 2; ++pq)
        #pragma unroll
        for (int e = 0; e < 16; ++e) acc[mw][pq][e] = 0.f;

    int ks = 0, l = 0;
    #pragma unroll 1
    for (int it = 0; it < 12; ++it) {
      bf16x8 Ac[3][2];
      loadA(Av, phb, ocg, ks, l, lane, Ac);

      bf16x8 Bf[4];
      const int col_t = ln31 + l;
      const int gneed = ks * 2 + lh;
      #pragma unroll
      for (int r = 0; r < 4; ++r) {
        const int lds_row = 2 * rh + r;
        Bf[r] = *(const bf16x8*)(xs + ((lds_row * XC + col_t) * 8 +
                                       (gneed ^ (col_t & 7))) * 8);
      }

      __builtin_amdgcn_s_setprio(1);
      #pragma unroll
      for (int r = 0; r < 4; ++r) {
        #pragma unroll
        for (int j = 0; j < 3; ++j) {
          const int mw = r - j;
          if (mw == 0 || mw == 1) {
            acc[mw][0] = __builtin_amdgcn_mfma_f32_32x32x16_bf16(
                Ac[j][0], Bf[r], acc[mw][0], 0, 0, 0);
            acc[mw][1] = __builtin_amdgcn_mfma_f32_32x32x16_bf16(
                Ac[j][1], Bf[r], acc[mw][1], 0, 0, 0);
          }
        }
      }
      __builtin_amdgcn_s_setprio(0);

      l = (l == 2) ? 0 : l + 1;
      ks = (l == 0) ? (ks + 1) & 3 : ks;
    }

    // epilogue: interleave pq in-register -> coalesced plain f32x2 stores
    #pragma unroll
    for (int mw = 0; mw < 2; ++mw) {
      const int p = 2 * (m0 + 2 * rh + mw) + pp;
      #pragma unroll
      for (int rr = 0; rr < 16; ++rr) {
        const int oc_loc = (rr & 3) + 8 * (rr >> 2) + 4 * lh;
        const int oc = ocg * 32 + oc_loc;
        size_t off =
            ((size_t)(b * 64 + oc) * 512 + p) * 512 + 2 * n0 + 2 * ln31;
        f32x2 v2;
        v2[0] = acc[mw][0][rr];
        v2[1] = acc[mw][1][rr];
        *(f32x2*)(out + off) = v2;
      }
    }

    if (t < 7) {
      __syncthreads(); // LDS consumed by all waves -> safe to overwrite
      stage_tile(xTg, b, m0, n0 + 32, xs, wv, lane);
      __syncthreads(); // stage complete (implicit vmcnt drain)
    }
  }
}

// ===================== fallback: f32 path =====================
__global__ __launch_bounds__(64) void pw_kernel(
    const float* __restrict__ w, const float* __restrict__ w_dense,
    const float* __restrict__ b_mod, const float* __restrict__ w_conv,
    float* __restrict__ PW) {
  const int oc = blockIdx.x;
  const int b = blockIdx.y;
  const int ic = threadIdx.x;
  float stv = style_of(w, w_dense, b_mod, b, ic);
  float E[6][6];
  compute_E(w_conv, stv, oc, E);
  #pragma unroll
  for (int pp = 0; pp < 2; ++pp)
    #pragma unroll
    for (int pq = 0; pq < 2; ++pq)
      #pragma unroll
      for (int j = 0; j < 3; ++j)
        #pragma unroll
        for (int l = 0; l < 3; ++l)
          PW[(((size_t)((b * 4 + pp * 2 + pq) * OC + oc) * IC + ic) * 9) +
             j * 3 + l] = E[2 * j + 1 - pp][2 * l + 1 - pq];
}

#define MT 16
#define NT 64
#define ICC 8
#define XROWS 18
#define XCOLS 66
#define XSTRIDE 68

__global__ __launch_bounds__(256) void conv_kernel(
    const float* __restrict__ x, const float* __restrict__ PW,
    float* __restrict__ out) {
  __shared__ float lds_x[ICC][XROWS][XSTRIDE];
  __shared__ float lds_w[4][ICC][9][4];

  const int tid = threadIdx.x;
  const int tn = tid & 15;
  const int tm = tid >> 4;
  const int bx = blockIdx.x;
  const int ntile = bx & 3;
  const int mtile = bx >> 2;
  const int ocg = blockIdx.y;
  const int b = blockIdx.z;
  const int m0 = mtile * MT;
  const int n0 = ntile * NT;

  float acc[4][4][4];
  #pragma unroll
  for (int o = 0; o < 4; ++o)
    #pragma unroll
    for (int ph = 0; ph < 4; ++ph)
      #pragma unroll
      for (int s = 0; s < 4; ++s) acc[o][ph][s] = 0.f;

  for (int ic0 = 0; ic0 < IC; ic0 += ICC) {
    __syncthreads();
    for (int ici = 0; ici < ICC; ++ici) {
      const float* xsrc = x + (size_t)(b * IC + ic0 + ici) * HH * HH;
      for (int rc = tid; rc < XROWS * XCOLS; rc += 256) {
        int r = rc / XCOLS;
        int c = rc - r * XCOLS;
        int gr = m0 - 1 + r;
        int gc = n0 - 1 + c;
        float v = 0.f;
        if ((unsigned)gr < HH && (unsigned)gc < HH) v = xsrc[gr * HH + gc];
        lds_x[ici][r][c] = v;
      }
    }
    for (int idx = tid; idx < 4 * ICC * 9 * 4; idx += 256) {
      int o = idx / (ICC * 9 * 4);
      int rem = idx - o * (ICC * 9 * 4);
      int ici = rem / 36;
      int r2 = rem - ici * 36;
      int t = r2 >> 2;
      int ph = r2 & 3;
      lds_w[o][ici][t][ph] =
          PW[(((size_t)((b * 4 + ph) * OC + (ocg * 4 + o)) * IC +
               (ic0 + ici)) * 9) + t];
    }
    __syncthreads();
    for (int ici = 0; ici < ICC; ++ici) {
      #pragma unroll
      for (int j = 0; j < 3; ++j) {
        const float* xr = &lds_x[ici][tm + j][tn * 4];
        float4 a4 = *(const float4*)xr;
        float2 a2 = *(const float2*)(xr + 4);
        float xv[6] = {a4.x, a4.y, a4.z, a4.w, a2.x, a2.y};
        #pragma unroll
        for (int l = 0; l < 3; ++l) {
          #pragma unroll
          for (int o = 0; o < 4; ++o) {
            float4 wv = *(const float4*)&lds_w[o][ici][j * 3 + l][0];
            #pragma unroll
            for (int s = 0; s < 4; ++s) {
              acc[o][0][s] = fmaf(wv.x, xv[l + s], acc[o][0][s]);
              acc[o][1][s] = fmaf(wv.y, xv[l + s], acc[o][1][s]);
              acc[o][2][s] = fmaf(wv.z, xv[l + s], acc[o][2][s]);
              acc[o][3][s] = fmaf(wv.w, xv[l + s], acc[o][3][s]);
            }
          }
        }
      }
    }
  }

  #pragma unroll
  for (int o = 0; o < 4; ++o) {
    #pragma unroll
    for (int pp = 0; pp < 2; ++pp) {
      const int p = 2 * (m0 + tm) + pp;
      float* dst = out +
          (((size_t)(b * OC + ocg * 4 + o) * 512 + p) * 512) + 2 * n0 + 8 * tn;
      float4 v0 = make_float4(acc[o][pp * 2 + 0][0], acc[o][pp * 2 + 1][0],
                              acc[o][pp * 2 + 0][1], acc[o][pp * 2 + 1][1]);
      float4 v1 = make_float4(acc[o][pp * 2 + 0][2], acc[o][pp * 2 + 1][2],
                              acc[o][pp * 2 + 0][3], acc[o][pp * 2 + 1][3]);
      *(float4*)dst = v0;
      *(float4*)(dst + 4) = v1;
    }
  }
}

extern "C" void kernel_launch(void* const* d_in, const int* in_sizes, int n_in,
                              void* d_out, int out_size, void* d_ws,
                              size_t ws_size, hipStream_t stream) {
  const float* x = (const float*)d_in[0];
  const float* w = (const float*)d_in[1];
  const float* w_conv = (const float*)d_in[2];
  const float* w_dense = (const float*)d_in[3];
  const float* b_mod = (const float*)d_in[4];
  float* out = (float*)d_out;

  const size_t PWF_BYTES = (size_t)8 * 4 * 9 * 2 * 4 * 64 * 8 * 2; // 2359296
  const size_t XTG_BYTES = (size_t)8 * PP * PP * 64 * 2;           // 68161536
  const size_t NEED_NEW = PWF_BYTES + XTG_BYTES;

  if (ws_size >= NEED_NEW) {
    __bf16* PWf = (__bf16*)d_ws;
    __bf16* xTg = (__bf16*)((char*)d_ws + PWF_BYTES);
    pre_kernel<<<dim3(2056 + 128), 256, 0, stream>>>(x, w, w_dense, b_mod,
                                                     w_conv, xTg, PWf);
    conv32s_kernel<<<dim3(512), 512, 0, stream>>>(xTg, PWf, out);
  } else {
    float* PW = (float*)d_ws;
    pw_kernel<<<dim3(OC, NB), 64, 0, stream>>>(w, w_dense, b_mod, w_conv, PW);
    conv_kernel<<<dim3(64, 16, NB), 256, 0, stream>>>(x, PW, out);
  }
}

// Round 17
// 255.371 us; speedup vs baseline: 1.1819x; 1.1819x over previous
//
#include <hip/hip_runtime.h>

#define NB 8
#define IC 64
#define OC 64
#define HH 256
#define WD 512
#define PP 258 // padded pitch

typedef __bf16 bf16x8 __attribute__((ext_vector_type(8)));
typedef float f32x16 __attribute__((ext_vector_type(16)));
typedef float f32x2 __attribute__((ext_vector_type(2)));

// Weight math: modulate, demodulate, compose with blur into E[6][6].
__device__ inline void compute_E(const float* __restrict__ w_conv, float stv,
                                 int oc, float E[6][6]) {
  const float coef_conv = 1.0f / 24.0f; // 1/sqrt(3*3*64)
  const float s = stv * coef_conv;
  const int ic = threadIdx.x & 63;

  float wm[3][3];
  float ssq = 0.f;
  #pragma unroll
  for (int kh = 0; kh < 3; ++kh)
    #pragma unroll
    for (int kw = 0; kw < 3; ++kw) {
      float v = w_conv[((kh * 3 + kw) * IC + ic) * OC + oc] * s;
      wm[kh][kw] = v;
      ssq += v * v;
    }
  #pragma unroll
  for (int off = 32; off > 0; off >>= 1) ssq += __shfl_xor(ssq, off);
  const float d = rsqrtf(ssq + 1e-8f);
  #pragma unroll
  for (int kh = 0; kh < 3; ++kh)
    #pragma unroll
    for (int kw = 0; kw < 3; ++kw) wm[kh][kw] *= d;

  const float g[4] = {0.25f, 0.75f, 0.75f, 0.25f};
  #pragma unroll
  for (int a = 0; a < 6; ++a)
    #pragma unroll
    for (int c = 0; c < 6; ++c) {
      float acc = 0.f;
      #pragma unroll
      for (int dh = 0; dh < 3; ++dh) {
        int u = a - dh;
        if (u < 0 || u > 3) continue;
        #pragma unroll
        for (int dw = 0; dw < 3; ++dw) {
          int v = c - dw;
          if (v < 0 || v > 3) continue;
          acc = fmaf(wm[dh][dw], g[u] * g[v], acc);
        }
      }
      E[a][c] = acc;
    }
}

__device__ inline float style_of(const float* __restrict__ w,
                                 const float* __restrict__ w_dense,
                                 const float* __restrict__ b_mod, int b,
                                 int ic) {
  const float coef_dense = 0.044194173824159216f; // 1/sqrt(512)
  const float* wr = w + b * WD;
  float acc = 0.f;
  for (int k = 0; k < WD; ++k) acc = fmaf(wr[k], w_dense[k * IC + ic], acc);
  return acc * coef_dense + b_mod[ic] + 1.0f;
}

// ---- fused pre-pass: xtp role (bid<2056) + pwfs role (bid>=2056) ----
// xtp: x [b][ic][m][n] f32 -> padded xTg [b][258][258][ic] bf16 (+guard)
// pwfs: PWf frag idx = ph*72 + tap*8 + ocg*4 + ks; 64 lanes x 16B each.
#define XS 268 // u16 LDS stride
__global__ __launch_bounds__(256) void pre_kernel(
    const float* __restrict__ x, const float* __restrict__ w,
    const float* __restrict__ w_dense, const float* __restrict__ b_mod,
    const float* __restrict__ w_conv, __bf16* __restrict__ xTg,
    __bf16* __restrict__ PWf) {
  __shared__ unsigned short buf[64 * XS];
  const int tid = threadIdx.x;
  const int bid = blockIdx.x;

  if (bid >= 2056) {
    // ---- pwfs role: 128 blocks, 4 waves each = one oc per wave ----
    const int bid2 = bid - 2056;
    const int b = bid2 >> 4;
    const int ocq = bid2 & 15;
    const int oc = ocq * 4 + (tid >> 6);
    const int ic = tid & 63;

    float stv = style_of(w, w_dense, b_mod, b, ic);
    float E[6][6];
    compute_E(w_conv, stv, oc, E);

    const int ks = ic >> 4;
    const int h = (ic >> 3) & 1;
    const int e = ic & 7;
    const int lane = (oc & 31) + 32 * h;
    const int ocg = oc >> 5;

    #pragma unroll
    for (int pp = 0; pp < 2; ++pp)
      #pragma unroll
      for (int pq = 0; pq < 2; ++pq) {
        const int ph = pp * 2 + pq;
        #pragma unroll
        for (int j = 0; j < 3; ++j)
          #pragma unroll
          for (int l = 0; l < 3; ++l) {
            const int tap = j * 3 + l;
            float val = E[2 * j + 1 - pp][2 * l + 1 - pq];
            size_t off =
                ((size_t)(((((b * 4 + ph) * 9 + tap) * 2 + ocg) * 4 + ks)) *
                     64 + lane) * 8 + e;
            PWf[off] = (__bf16)val;
          }
      }
    return;
  }

  // ---- xtp role ----
  const int m = bid % 257; // 0..256 ; 256 = guard-zero pass
  const int b = bid / 257;

  if (m == 256) {
    uint4 z = make_uint4(0, 0, 0, 0);
    for (int i = tid; i < 8224; i += 256) {
      int pix = i >> 3;
      int sub = i & 7;
      int pr, pc;
      if (pix < 258) {
        pr = 0; pc = pix;
      } else if (pix < 516) {
        pr = 257; pc = pix - 258;
      } else {
        int rem = pix - 516; // 0..511
        pr = 1 + (rem >> 1);
        pc = (rem & 1) ? 257 : 0;
      }
      *(uint4*)(xTg + ((size_t)(b * PP + pr) * PP + pc) * 64 + sub * 8) = z;
    }
    return;
  }

  const int ln = tid & 63, grp = tid >> 6;
  #pragma unroll
  for (int p = 0; p < 16; ++p) {
    const int ic = p * 4 + grp;
    float4 v = *(const float4*)(x + ((size_t)(b * 64 + ic) * 256 + m) * 256 +
                                ln * 4);
    ushort4 u4;
    u4.x = __builtin_bit_cast(unsigned short, (__bf16)v.x);
    u4.y = __builtin_bit_cast(unsigned short, (__bf16)v.y);
    u4.z = __builtin_bit_cast(unsigned short, (__bf16)v.z);
    u4.w = __builtin_bit_cast(unsigned short, (__bf16)v.w);
    *(ushort4*)&buf[ic * XS + ln * 4] = u4;
  }
  __syncthreads();
  #pragma unroll
  for (int it = 0; it < 8; ++it) {
    int pix = it * 32 + (tid >> 3);
    int g = tid & 7;
    bf16x8 o;
    #pragma unroll
    for (int e = 0; e < 8; ++e)
      o[e] = __builtin_bit_cast(__bf16, buf[(g * 8 + e) * XS + pix]);
    *(bf16x8*)(xTg + ((size_t)(b * PP + m + 1) * PP + (pix + 1)) * 64 +
               g * 8) = o;
  }
}

// ---- streaming MFMA conv, 2 blocks/CU (R7 structure, verbatim) ----
#define CMT 8
#define XR 10 // CMT+2
#define XC 34 // cols (pixels), storage stride

__device__ __forceinline__ void loadA(const bf16x8* __restrict__ Av, int phb,
                                      int ocg, int ks, int l, int lane,
                                      bf16x8 A[3][2]) {
  #pragma unroll
  for (int j = 0; j < 3; ++j) {
    const int tap = j * 3 + l;
    #pragma unroll
    for (int pq = 0; pq < 2; ++pq)
      A[j][pq] =
          Av[(size_t)((((phb + pq) * 9 + tap) * 2 + ocg) * 4 + ks) * 64 + lane];
  }
}

#define GLD_LDS(src, dst)                                                \
  __builtin_amdgcn_global_load_lds(                                      \
      (const __attribute__((address_space(1))) void*)(src),              \
      (__attribute__((address_space(3))) void*)(dst), 16, 0, 0)

// stage one 10x34 tile (rows split across 8 waves) via global_load_lds.
// LDS linear; source granule pre-swizzled: slot s at pixel col holds
// granule s ^ (col&7), matching the reader's XOR.
__device__ __forceinline__ void stage_tile(const __bf16* __restrict__ xTg,
                                           int b, int m0, int n0,
                                           __bf16* xsbuf, int wv, int lane) {
  const int r0 = (XR * wv) >> 3;
  const int r1 = (XR * (wv + 1)) >> 3;
  for (int row = r0; row < r1; ++row) {
    const size_t srow = (size_t)(b * PP + m0 + row) * PP;
    __bf16* ldsrow = xsbuf + row * (XC * 64);
    #pragma unroll
    for (int q = 0; q < 4; ++q) {
      int pix = q * 8 + (lane >> 3);
      int g = (lane & 7) ^ (pix & 7);
      const __bf16* src = xTg + (srow + (n0 + pix)) * 64 + g * 8;
      GLD_LDS(src, ldsrow + q * 512);
    }
    if (lane < 16) {
      int pix = 32 + (lane >> 3);
      int g = (lane & 7) ^ (pix & 7);
      const __bf16* src = xTg + (srow + (n0 + pix)) * 64 + g * 8;
      GLD_LDS(src, ldsrow + 2048);
    }
  }
}

__global__ __launch_bounds__(512, 4) void conv32s_kernel(
    const __bf16* __restrict__ xTg, const __bf16* __restrict__ PWf,
    float* __restrict__ out) {
  __shared__ __bf16 xs[XR * XC * 64]; // 43520 B single buffer

  const int tid = threadIdx.x;
  const int lane = tid & 63;
  const int wv = tid >> 6; // 0..7
  const int pp = wv & 1;
  const int rh = wv >> 1; // 0..3, 2 rows each

  const int bid = blockIdx.x; // 512 = 8b * 2ocg * 32mtile (raw order)
  const int mtile = bid & 31;
  const int ocg = (bid >> 5) & 1;
  const int b = bid >> 6;
  const int m0 = mtile * CMT;

  const int ln31 = lane & 31;
  const int lh = lane >> 5;
  const bf16x8* Av = (const bf16x8*)PWf;
  const int phb = b * 4 + pp * 2;

  stage_tile(xTg, b, m0, 0, xs, wv, lane);
  __syncthreads();

  #pragma unroll 1
  for (int t = 0; t < 8; ++t) {
    const int n0 = t * 32;

    f32x16 acc[2][2]; // [mw][pq]
    #pragma unroll
    for (int mw = 0; mw < 2; ++mw)
      #pragma unroll
      for (int pq = 0; pq < 2; ++pq)
        #pragma unroll
        for (int e = 0; e < 16; ++e) acc[mw][pq][e] = 0.f;

    int ks = 0, l = 0;
    #pragma unroll 1
    for (int it = 0; it < 12; ++it) {
      bf16x8 Ac[3][2];
      loadA(Av, phb, ocg, ks, l, lane, Ac);

      bf16x8 Bf[4];
      const int col_t = ln31 + l;
      const int gneed = ks * 2 + lh;
      #pragma unroll
      for (int r = 0; r < 4; ++r) {
        const int lds_row = 2 * rh + r;
        Bf[r] = *(const bf16x8*)(xs + ((lds_row * XC + col_t) * 8 +
                                       (gneed ^ (col_t & 7))) * 8);
      }

      __builtin_amdgcn_s_setprio(1);
      #pragma unroll
      for (int r = 0; r < 4; ++r) {
        #pragma unroll
        for (int j = 0; j < 3; ++j) {
          const int mw = r - j;
          if (mw == 0 || mw == 1) {
            acc[mw][0] = __builtin_amdgcn_mfma_f32_32x32x16_bf16(
                Ac[j][0], Bf[r], acc[mw][0], 0, 0, 0);
            acc[mw][1] = __builtin_amdgcn_mfma_f32_32x32x16_bf16(
                Ac[j][1], Bf[r], acc[mw][1], 0, 0, 0);
          }
        }
      }
      __builtin_amdgcn_s_setprio(0);

      l = (l == 2) ? 0 : l + 1;
      ks = (l == 0) ? (ks + 1) & 3 : ks;
    }

    // epilogue: interleave pq in-register -> coalesced nontemporal stores
    #pragma unroll
    for (int mw = 0; mw < 2; ++mw) {
      const int p = 2 * (m0 + 2 * rh + mw) + pp;
      #pragma unroll
      for (int rr = 0; rr < 16; ++rr) {
        const int oc_loc = (rr & 3) + 8 * (rr >> 2) + 4 * lh;
        const int oc = ocg * 32 + oc_loc;
        size_t off =
            ((size_t)(b * 64 + oc) * 512 + p) * 512 + 2 * n0 + 2 * ln31;
        f32x2 v2;
        v2[0] = acc[mw][0][rr];
        v2[1] = acc[mw][1][rr];
        __builtin_nontemporal_store(v2, (f32x2*)(out + off));
      }
    }

    if (t < 7) {
      __syncthreads(); // LDS consumed by all waves -> safe to overwrite
      stage_tile(xTg, b, m0, n0 + 32, xs, wv, lane);
      __syncthreads(); // stage complete (implicit vmcnt drain)
    }
  }
}

// ===================== fallback: f32 path =====================
__global__ __launch_bounds__(64) void pw_kernel(
    const float* __restrict__ w, const float* __restrict__ w_dense,
    const float* __restrict__ b_mod, const float* __restrict__ w_conv,
    float* __restrict__ PW) {
  const int oc = blockIdx.x;
  const int b = blockIdx.y;
  const int ic = threadIdx.x;
  float stv = style_of(w, w_dense, b_mod, b, ic);
  float E[6][6];
  compute_E(w_conv, stv, oc, E);
  #pragma unroll
  for (int pp = 0; pp < 2; ++pp)
    #pragma unroll
    for (int pq = 0; pq < 2; ++pq)
      #pragma unroll
      for (int j = 0; j < 3; ++j)
        #pragma unroll
        for (int l = 0; l < 3; ++l)
          PW[(((size_t)((b * 4 + pp * 2 + pq) * OC + oc) * IC + ic) * 9) +
             j * 3 + l] = E[2 * j + 1 - pp][2 * l + 1 - pq];
}

#define MT 16
#define NT 64
#define ICC 8
#define XROWS 18
#define XCOLS 66
#define XSTRIDE 68

__global__ __launch_bounds__(256) void conv_kernel(
    const float* __restrict__ x, const float* __restrict__ PW,
    float* __restrict__ out) {
  __shared__ float lds_x[ICC][XROWS][XSTRIDE];
  __shared__ float lds_w[4][ICC][9][4];

  const int tid = threadIdx.x;
  const int tn = tid & 15;
  const int tm = tid >> 4;
  const int bx = blockIdx.x;
  const int ntile = bx & 3;
  const int mtile = bx >> 2;
  const int ocg = blockIdx.y;
  const int b = blockIdx.z;
  const int m0 = mtile * MT;
  const int n0 = ntile * NT;

  float acc[4][4][4];
  #pragma unroll
  for (int o = 0; o < 4; ++o)
    #pragma unroll
    for (int ph = 0; ph < 4; ++ph)
      #pragma unroll
      for (int s = 0; s < 4; ++s) acc[o][ph][s] = 0.f;

  for (int ic0 = 0; ic0 < IC; ic0 += ICC) {
    __syncthreads();
    for (int ici = 0; ici < ICC; ++ici) {
      const float* xsrc = x + (size_t)(b * IC + ic0 + ici) * HH * HH;
      for (int rc = tid; rc < XROWS * XCOLS; rc += 256) {
        int r = rc / XCOLS;
        int c = rc - r * XCOLS;
        int gr = m0 - 1 + r;
        int gc = n0 - 1 + c;
        float v = 0.f;
        if ((unsigned)gr < HH && (unsigned)gc < HH) v = xsrc[gr * HH + gc];
        lds_x[ici][r][c] = v;
      }
    }
    for (int idx = tid; idx < 4 * ICC * 9 * 4; idx += 256) {
      int o = idx / (ICC * 9 * 4);
      int rem = idx - o * (ICC * 9 * 4);
      int ici = rem / 36;
      int r2 = rem - ici * 36;
      int t = r2 >> 2;
      int ph = r2 & 3;
      lds_w[o][ici][t][ph] =
          PW[(((size_t)((b * 4 + ph) * OC + (ocg * 4 + o)) * IC +
               (ic0 + ici)) * 9) + t];
    }
    __syncthreads();
    for (int ici = 0; ici < ICC; ++ici) {
      #pragma unroll
      for (int j = 0; j < 3; ++j) {
        const float* xr = &lds_x[ici][tm + j][tn * 4];
        float4 a4 = *(const float4*)xr;
        float2 a2 = *(const float2*)(xr + 4);
        float xv[6] = {a4.x, a4.y, a4.z, a4.w, a2.x, a2.y};
        #pragma unroll
        for (int l = 0; l < 3; ++l) {
          #pragma unroll
          for (int o = 0; o < 4; ++o) {
            float4 wv = *(const float4*)&lds_w[o][ici][j * 3 + l][0];
            #pragma unroll
            for (int s = 0; s < 4; ++s) {
              acc[o][0][s] = fmaf(wv.x, xv[l + s], acc[o][0][s]);
              acc[o][1][s] = fmaf(wv.y, xv[l + s], acc[o][1][s]);
              acc[o][2][s] = fmaf(wv.z, xv[l + s], acc[o][2][s]);
              acc[o][3][s] = fmaf(wv.w, xv[l + s], acc[o][3][s]);
            }
          }
        }
      }
    }
  }

  #pragma unroll
  for (int o = 0; o < 4; ++o) {
    #pragma unroll
    for (int pp = 0; pp < 2; ++pp) {
      const int p = 2 * (m0 + tm) + pp;
      float* dst = out +
          (((size_t)(b * OC + ocg * 4 + o) * 512 + p) * 512) + 2 * n0 + 8 * tn;
      float4 v0 = make_float4(acc[o][pp * 2 + 0][0], acc[o][pp * 2 + 1][0],
                              acc[o][pp * 2 + 0][1], acc[o][pp * 2 + 1][1]);
      float4 v1 = make_float4(acc[o][pp * 2 + 0][2], acc[o][pp * 2 + 1][2],
                              acc[o][pp * 2 + 0][3], acc[o][pp * 2 + 1][3]);
      *(float4*)dst = v0;
      *(float4*)(dst + 4) = v1;
    }
  }
}

extern "C" void kernel_launch(void* const* d_in, const int* in_sizes, int n_in,
                              void* d_out, int out_size, void* d_ws,
                              size_t ws_size, hipStream_t stream) {
  const float* x = (const float*)d_in[0];
  const float* w = (const float*)d_in[1];
  const float* w_conv = (const float*)d_in[2];
  const float* w_dense = (const float*)d_in[3];
  const float* b_mod = (const float*)d_in[4];
  float* out = (float*)d_out;

  const size_t PWF_BYTES = (size_t)8 * 4 * 9 * 2 * 4 * 64 * 8 * 2; // 2359296
  const size_t XTG_BYTES = (size_t)8 * PP * PP * 64 * 2;           // 68161536
  const size_t NEED_NEW = PWF_BYTES + XTG_BYTES;

  if (ws_size >= NEED_NEW) {
    __bf16* PWf = (__bf16*)d_ws;
    __bf16* xTg = (__bf16*)((char*)d_ws + PWF_BYTES);
    pre_kernel<<<dim3(2056 + 128), 256, 0, stream>>>(x, w, w_dense, b_mod,
                                                     w_conv, xTg, PWf);
    conv32s_kernel<<<dim3(512), 512, 0, stream>>>(xTg, PWf, out);
  } else {
    float* PW = (float*)d_ws;
    pw_kernel<<<dim3(OC, NB), 64, 0, stream>>>(w, w_dense, b_mod, w_conv, PW);
    conv_kernel<<<dim3(64, 16, NB), 256, 0, stream>>>(x, PW, out);
  }
}

// Round 18
// 250.277 us; speedup vs baseline: 1.2059x; 1.0204x over previous
//
#include <hip/hip_runtime.h>

#define NB 8
#define IC 64
#define OC 64
#define HH 256
#define WD 512
#define PP 258 // padded pitch

typedef __bf16 bf16x8 __attribute__((ext_vector_type(8)));
typedef float f32x16 __attribute__((ext_vector_type(16)));
typedef float f32x2 __attribute__((ext_vector_type(2)));

// Weight math: modulate, demodulate, compose with blur into E[6][6].
__device__ inline void compute_E(const float* __restrict__ w_conv, float stv,
                                 int oc, float E[6][6]) {
  const float coef_conv = 1.0f / 24.0f; // 1/sqrt(3*3*64)
  const float s = stv * coef_conv;
  const int ic = threadIdx.x & 63;

  float wm[3][3];
  float ssq = 0.f;
  #pragma unroll
  for (int kh = 0; kh < 3; ++kh)
    #pragma unroll
    for (int kw = 0; kw < 3; ++kw) {
      float v = w_conv[((kh * 3 + kw) * IC + ic) * OC + oc] * s;
      wm[kh][kw] = v;
      ssq += v * v;
    }
  #pragma unroll
  for (int off = 32; off > 0; off >>= 1) ssq += __shfl_xor(ssq, off);
  const float d = rsqrtf(ssq + 1e-8f);
  #pragma unroll
  for (int kh = 0; kh < 3; ++kh)
    #pragma unroll
    for (int kw = 0; kw < 3; ++kw) wm[kh][kw] *= d;

  const float g[4] = {0.25f, 0.75f, 0.75f, 0.25f};
  #pragma unroll
  for (int a = 0; a < 6; ++a)
    #pragma unroll
    for (int c = 0; c < 6; ++c) {
      float acc = 0.f;
      #pragma unroll
      for (int dh = 0; dh < 3; ++dh) {
        int u = a - dh;
        if (u < 0 || u > 3) continue;
        #pragma unroll
        for (int dw = 0; dw < 3; ++dw) {
          int v = c - dw;
          if (v < 0 || v > 3) continue;
          acc = fmaf(wm[dh][dw], g[u] * g[v], acc);
        }
      }
      E[a][c] = acc;
    }
}

__device__ inline float style_of(const float* __restrict__ w,
                                 const float* __restrict__ w_dense,
                                 const float* __restrict__ b_mod, int b,
                                 int ic) {
  const float coef_dense = 0.044194173824159216f; // 1/sqrt(512)
  const float* wr = w + b * WD;
  float acc = 0.f;
  for (int k = 0; k < WD; ++k) acc = fmaf(wr[k], w_dense[k * IC + ic], acc);
  return acc * coef_dense + b_mod[ic] + 1.0f;
}

// ---- fused pre-pass: xtp role (bid<2056) + pwfs role (bid>=2056) ----
// xtp: x [b][ic][m][n] f32 -> padded xTg [b][258][258][ic] bf16 (+guard)
// pwfs: PWf frag idx = ph*72 + tap*8 + ocg*4 + ks; 64 lanes x 16B each.
#define XS 268 // u16 LDS stride
__global__ __launch_bounds__(256) void pre_kernel(
    const float* __restrict__ x, const float* __restrict__ w,
    const float* __restrict__ w_dense, const float* __restrict__ b_mod,
    const float* __restrict__ w_conv, __bf16* __restrict__ xTg,
    __bf16* __restrict__ PWf) {
  __shared__ unsigned short buf[64 * XS];
  const int tid = threadIdx.x;
  const int bid = blockIdx.x;

  if (bid >= 2056) {
    // ---- pwfs role: 128 blocks, 4 waves each = one oc per wave ----
    const int bid2 = bid - 2056;
    const int b = bid2 >> 4;
    const int ocq = bid2 & 15;
    const int oc = ocq * 4 + (tid >> 6);
    const int ic = tid & 63;

    float stv = style_of(w, w_dense, b_mod, b, ic);
    float E[6][6];
    compute_E(w_conv, stv, oc, E);

    const int ks = ic >> 4;
    const int h = (ic >> 3) & 1;
    const int e = ic & 7;
    const int lane = (oc & 31) + 32 * h;
    const int ocg = oc >> 5;

    #pragma unroll
    for (int pp = 0; pp < 2; ++pp)
      #pragma unroll
      for (int pq = 0; pq < 2; ++pq) {
        const int ph = pp * 2 + pq;
        #pragma unroll
        for (int j = 0; j < 3; ++j)
          #pragma unroll
          for (int l = 0; l < 3; ++l) {
            const int tap = j * 3 + l;
            float val = E[2 * j + 1 - pp][2 * l + 1 - pq];
            size_t off =
                ((size_t)(((((b * 4 + ph) * 9 + tap) * 2 + ocg) * 4 + ks)) *
                     64 + lane) * 8 + e;
            PWf[off] = (__bf16)val;
          }
      }
    return;
  }

  // ---- xtp role ----
  const int m = bid % 257; // 0..256 ; 256 = guard-zero pass
  const int b = bid / 257;

  if (m == 256) {
    uint4 z = make_uint4(0, 0, 0, 0);
    for (int i = tid; i < 8224; i += 256) {
      int pix = i >> 3;
      int sub = i & 7;
      int pr, pc;
      if (pix < 258) {
        pr = 0; pc = pix;
      } else if (pix < 516) {
        pr = 257; pc = pix - 258;
      } else {
        int rem = pix - 516; // 0..511
        pr = 1 + (rem >> 1);
        pc = (rem & 1) ? 257 : 0;
      }
      *(uint4*)(xTg + ((size_t)(b * PP + pr) * PP + pc) * 64 + sub * 8) = z;
    }
    return;
  }

  const int ln = tid & 63, grp = tid >> 6;
  #pragma unroll
  for (int p = 0; p < 16; ++p) {
    const int ic = p * 4 + grp;
    float4 v = *(const float4*)(x + ((size_t)(b * 64 + ic) * 256 + m) * 256 +
                                ln * 4);
    ushort4 u4;
    u4.x = __builtin_bit_cast(unsigned short, (__bf16)v.x);
    u4.y = __builtin_bit_cast(unsigned short, (__bf16)v.y);
    u4.z = __builtin_bit_cast(unsigned short, (__bf16)v.z);
    u4.w = __builtin_bit_cast(unsigned short, (__bf16)v.w);
    *(ushort4*)&buf[ic * XS + ln * 4] = u4;
  }
  __syncthreads();
  #pragma unroll
  for (int it = 0; it < 8; ++it) {
    int pix = it * 32 + (tid >> 3);
    int g = tid & 7;
    bf16x8 o;
    #pragma unroll
    for (int e = 0; e < 8; ++e)
      o[e] = __builtin_bit_cast(__bf16, buf[(g * 8 + e) * XS + pix]);
    *(bf16x8*)(xTg + ((size_t)(b * PP + m + 1) * PP + (pix + 1)) * 64 +
               g * 8) = o;
  }
}

// ---- small-block streaming MFMA conv: 256 thr, ~4 blocks/CU resident ----
#define CMT 4
#define XR 6  // CMT+2
#define XC 34 // cols (pixels), storage stride

__device__ __forceinline__ void loadA(const bf16x8* __restrict__ Av, int phb,
                                      int ocg, int ks, int l, int lane,
                                      bf16x8 A[3][2]) {
  #pragma unroll
  for (int j = 0; j < 3; ++j) {
    const int tap = j * 3 + l;
    #pragma unroll
    for (int pq = 0; pq < 2; ++pq)
      A[j][pq] =
          Av[(size_t)((((phb + pq) * 9 + tap) * 2 + ocg) * 4 + ks) * 64 + lane];
  }
}

#define GLD_LDS(src, dst)                                                \
  __builtin_amdgcn_global_load_lds(                                      \
      (const __attribute__((address_space(1))) void*)(src),              \
      (__attribute__((address_space(3))) void*)(dst), 16, 0, 0)

// stage one 6x34 tile (rows split across 4 waves) via global_load_lds.
// LDS linear; source granule pre-swizzled: slot s at pixel col holds
// granule s ^ (col&7), matching the reader's XOR.
__device__ __forceinline__ void stage_tile(const __bf16* __restrict__ xTg,
                                           int b, int m0, int n0,
                                           __bf16* xsbuf, int wv, int lane) {
  const int r0 = (XR * wv) >> 2;
  const int r1 = (XR * (wv + 1)) >> 2;
  for (int row = r0; row < r1; ++row) {
    const size_t srow = (size_t)(b * PP + m0 + row) * PP;
    __bf16* ldsrow = xsbuf + row * (XC * 64);
    #pragma unroll
    for (int q = 0; q < 4; ++q) {
      int pix = q * 8 + (lane >> 3);
      int g = (lane & 7) ^ (pix & 7);
      const __bf16* src = xTg + (srow + (n0 + pix)) * 64 + g * 8;
      GLD_LDS(src, ldsrow + q * 512);
    }
    if (lane < 16) {
      int pix = 32 + (lane >> 3);
      int g = (lane & 7) ^ (pix & 7);
      const __bf16* src = xTg + (srow + (n0 + pix)) * 64 + g * 8;
      GLD_LDS(src, ldsrow + 2048);
    }
  }
}

__global__ __launch_bounds__(256, 4) void conv32h_kernel(
    const __bf16* __restrict__ xTg, const __bf16* __restrict__ PWf,
    float* __restrict__ out) {
  __shared__ __bf16 xs[XR * XC * 64]; // 26112 B single buffer

  const int tid = threadIdx.x;
  const int lane = tid & 63;
  const int wv = tid >> 6; // 0..3
  const int pp = wv & 1;
  const int rh = wv >> 1; // 0..1, 2 rows each

  const int bid = blockIdx.x; // 1024 = 8b * 2ocg * 64mtile (raw order)
  const int mtile = bid & 63;
  const int ocg = (bid >> 6) & 1;
  const int b = bid >> 7;
  const int m0 = mtile * CMT;

  const int ln31 = lane & 31;
  const int lh = lane >> 5;
  const bf16x8* Av = (const bf16x8*)PWf;
  const int phb = b * 4 + pp * 2;

  stage_tile(xTg, b, m0, 0, xs, wv, lane);
  __syncthreads();

  #pragma unroll 1
  for (int t = 0; t < 8; ++t) {
    const int n0 = t * 32;

    f32x16 acc[2][2]; // [mw][pq]
    #pragma unroll
    for (int mw = 0; mw < 2; ++mw)
      #pragma unroll
      for (int pq = 0; pq < 2; ++pq)
        #pragma unroll
        for (int e = 0; e < 16; ++e) acc[mw][pq][e] = 0.f;

    int ks = 0, l = 0;
    #pragma unroll 1
    for (int it = 0; it < 12; ++it) {
      bf16x8 Ac[3][2];
      loadA(Av, phb, ocg, ks, l, lane, Ac);

      bf16x8 Bf[4];
      const int col_t = ln31 + l;
      const int gneed = ks * 2 + lh;
      #pragma unroll
      for (int r = 0; r < 4; ++r) {
        const int lds_row = 2 * rh + r;
        Bf[r] = *(const bf16x8*)(xs + ((lds_row * XC + col_t) * 8 +
                                       (gneed ^ (col_t & 7))) * 8);
      }

      __builtin_amdgcn_s_setprio(1);
      #pragma unroll
      for (int r = 0; r < 4; ++r) {
        #pragma unroll
        for (int j = 0; j < 3; ++j) {
          const int mw = r - j;
          if (mw == 0 || mw == 1) {
            acc[mw][0] = __builtin_amdgcn_mfma_f32_32x32x16_bf16(
                Ac[j][0], Bf[r], acc[mw][0], 0, 0, 0);
            acc[mw][1] = __builtin_amdgcn_mfma_f32_32x32x16_bf16(
                Ac[j][1], Bf[r], acc[mw][1], 0, 0, 0);
          }
        }
      }
      __builtin_amdgcn_s_setprio(0);

      l = (l == 2) ? 0 : l + 1;
      ks = (l == 0) ? (ks + 1) & 3 : ks;
    }

    // epilogue: interleave pq in-register -> coalesced nontemporal stores
    #pragma unroll
    for (int mw = 0; mw < 2; ++mw) {
      const int p = 2 * (m0 + 2 * rh + mw) + pp;
      #pragma unroll
      for (int rr = 0; rr < 16; ++rr) {
        const int oc_loc = (rr & 3) + 8 * (rr >> 2) + 4 * lh;
        const int oc = ocg * 32 + oc_loc;
        size_t off =
            ((size_t)(b * 64 + oc) * 512 + p) * 512 + 2 * n0 + 2 * ln31;
        f32x2 v2;
        v2[0] = acc[mw][0][rr];
        v2[1] = acc[mw][1][rr];
        __builtin_nontemporal_store(v2, (f32x2*)(out + off));
      }
    }

    if (t < 7) {
      __syncthreads(); // LDS consumed by all waves -> safe to overwrite
      stage_tile(xTg, b, m0, n0 + 32, xs, wv, lane);
      __syncthreads(); // stage complete (implicit vmcnt drain)
    }
  }
}

// ===================== fallback: f32 path =====================
__global__ __launch_bounds__(64) void pw_kernel(
    const float* __restrict__ w, const float* __restrict__ w_dense,
    const float* __restrict__ b_mod, const float* __restrict__ w_conv,
    float* __restrict__ PW) {
  const int oc = blockIdx.x;
  const int b = blockIdx.y;
  const int ic = threadIdx.x;
  float stv = style_of(w, w_dense, b_mod, b, ic);
  float E[6][6];
  compute_E(w_conv, stv, oc, E);
  #pragma unroll
  for (int pp = 0; pp < 2; ++pp)
    #pragma unroll
    for (int pq = 0; pq < 2; ++pq)
      #pragma unroll
      for (int j = 0; j < 3; ++j)
        #pragma unroll
        for (int l = 0; l < 3; ++l)
          PW[(((size_t)((b * 4 + pp * 2 + pq) * OC + oc) * IC + ic) * 9) +
             j * 3 + l] = E[2 * j + 1 - pp][2 * l + 1 - pq];
}

#define MT 16
#define NT 64
#define ICC 8
#define XROWS 18
#define XCOLS 66
#define XSTRIDE 68

__global__ __launch_bounds__(256) void conv_kernel(
    const float* __restrict__ x, const float* __restrict__ PW,
    float* __restrict__ out) {
  __shared__ float lds_x[ICC][XROWS][XSTRIDE];
  __shared__ float lds_w[4][ICC][9][4];

  const int tid = threadIdx.x;
  const int tn = tid & 15;
  const int tm = tid >> 4;
  const int bx = blockIdx.x;
  const int ntile = bx & 3;
  const int mtile = bx >> 2;
  const int ocg = blockIdx.y;
  const int b = blockIdx.z;
  const int m0 = mtile * MT;
  const int n0 = ntile * NT;

  float acc[4][4][4];
  #pragma unroll
  for (int o = 0; o < 4; ++o)
    #pragma unroll
    for (int ph = 0; ph < 4; ++ph)
      #pragma unroll
      for (int s = 0; s < 4; ++s) acc[o][ph][s] = 0.f;

  for (int ic0 = 0; ic0 < IC; ic0 += ICC) {
    __syncthreads();
    for (int ici = 0; ici < ICC; ++ici) {
      const float* xsrc = x + (size_t)(b * IC + ic0 + ici) * HH * HH;
      for (int rc = tid; rc < XROWS * XCOLS; rc += 256) {
        int r = rc / XCOLS;
        int c = rc - r * XCOLS;
        int gr = m0 - 1 + r;
        int gc = n0 - 1 + c;
        float v = 0.f;
        if ((unsigned)gr < HH && (unsigned)gc < HH) v = xsrc[gr * HH + gc];
        lds_x[ici][r][c] = v;
      }
    }
    for (int idx = tid; idx < 4 * ICC * 9 * 4; idx += 256) {
      int o = idx / (ICC * 9 * 4);
      int rem = idx - o * (ICC * 9 * 4);
      int ici = rem / 36;
      int r2 = rem - ici * 36;
      int t = r2 >> 2;
      int ph = r2 & 3;
      lds_w[o][ici][t][ph] =
          PW[(((size_t)((b * 4 + ph) * OC + (ocg * 4 + o)) * IC +
               (ic0 + ici)) * 9) + t];
    }
    __syncthreads();
    for (int ici = 0; ici < ICC; ++ici) {
      #pragma unroll
      for (int j = 0; j < 3; ++j) {
        const float* xr = &lds_x[ici][tm + j][tn * 4];
        float4 a4 = *(const float4*)xr;
        float2 a2 = *(const float2*)(xr + 4);
        float xv[6] = {a4.x, a4.y, a4.z, a4.w, a2.x, a2.y};
        #pragma unroll
        for (int l = 0; l < 3; ++l) {
          #pragma unroll
          for (int o = 0; o < 4; ++o) {
            float4 wv = *(const float4*)&lds_w[o][ici][j * 3 + l][0];
            #pragma unroll
            for (int s = 0; s < 4; ++s) {
              acc[o][0][s] = fmaf(wv.x, xv[l + s], acc[o][0][s]);
              acc[o][1][s] = fmaf(wv.y, xv[l + s], acc[o][1][s]);
              acc[o][2][s] = fmaf(wv.z, xv[l + s], acc[o][2][s]);
              acc[o][3][s] = fmaf(wv.w, xv[l + s], acc[o][3][s]);
            }
          }
        }
      }
    }
  }

  #pragma unroll
  for (int o = 0; o < 4; ++o) {
    #pragma unroll
    for (int pp = 0; pp < 2; ++pp) {
      const int p = 2 * (m0 + tm) + pp;
      float* dst = out +
          (((size_t)(b * OC + ocg * 4 + o) * 512 + p) * 512) + 2 * n0 + 8 * tn;
      float4 v0 = make_float4(acc[o][pp * 2 + 0][0], acc[o][pp * 2 + 1][0],
                              acc[o][pp * 2 + 0][1], acc[o][pp * 2 + 1][1]);
      float4 v1 = make_float4(acc[o][pp * 2 + 0][2], acc[o][pp * 2 + 1][2],
                              acc[o][pp * 2 + 0][3], acc[o][pp * 2 + 1][3]);
      *(float4*)dst = v0;
      *(float4*)(dst + 4) = v1;
    }
  }
}

extern "C" void kernel_launch(void* const* d_in, const int* in_sizes, int n_in,
                              void* d_out, int out_size, void* d_ws,
                              size_t ws_size, hipStream_t stream) {
  const float* x = (const float*)d_in[0];
  const float* w = (const float*)d_in[1];
  const float* w_conv = (const float*)d_in[2];
  const float* w_dense = (const float*)d_in[3];
  const float* b_mod = (const float*)d_in[4];
  float* out = (float*)d_out;

  const size_t PWF_BYTES = (size_t)8 * 4 * 9 * 2 * 4 * 64 * 8 * 2; // 2359296
  const size_t XTG_BYTES = (size_t)8 * PP * PP * 64 * 2;           // 68161536
  const size_t NEED_NEW = PWF_BYTES + XTG_BYTES;

  if (ws_size >= NEED_NEW) {
    __bf16* PWf = (__bf16*)d_ws;
    __bf16* xTg = (__bf16*)((char*)d_ws + PWF_BYTES);
    pre_kernel<<<dim3(2056 + 128), 256, 0, stream>>>(x, w, w_dense, b_mod,
                                                     w_conv, xTg, PWf);
    conv32h_kernel<<<dim3(1024), 256, 0, stream>>>(xTg, PWf, out);
  } else {
    float* PW = (float*)d_ws;
    pw_kernel<<<dim3(OC, NB), 64, 0, stream>>>(w, w_dense, b_mod, w_conv, PW);
    conv_kernel<<<dim3(64, 16, NB), 256, 0, stream>>>(x, PW, out);
  }
}

// Round 19
// 250.120 us; speedup vs baseline: 1.2067x; 1.0006x over previous
//
#include <hip/hip_runtime.h>

#define NB 8
#define IC 64
#define OC 64
#define HH 256
#define WD 512
#define PP 258 // padded pitch

typedef __bf16 bf16x8 __attribute__((ext_vector_type(8)));
typedef float f32x16 __attribute__((ext_vector_type(16)));
typedef float f32x2 __attribute__((ext_vector_type(2)));

// Weight math: modulate, demodulate, compose with blur into E[6][6].
__device__ inline void compute_E(const float* __restrict__ w_conv, float stv,
                                 int oc, float E[6][6]) {
  const float coef_conv = 1.0f / 24.0f; // 1/sqrt(3*3*64)
  const float s = stv * coef_conv;
  const int ic = threadIdx.x & 63;

  float wm[3][3];
  float ssq = 0.f;
  #pragma unroll
  for (int kh = 0; kh < 3; ++kh)
    #pragma unroll
    for (int kw = 0; kw < 3; ++kw) {
      float v = w_conv[((kh * 3 + kw) * IC + ic) * OC + oc] * s;
      wm[kh][kw] = v;
      ssq += v * v;
    }
  #pragma unroll
  for (int off = 32; off > 0; off >>= 1) ssq += __shfl_xor(ssq, off);
  const float d = rsqrtf(ssq + 1e-8f);
  #pragma unroll
  for (int kh = 0; kh < 3; ++kh)
    #pragma unroll
    for (int kw = 0; kw < 3; ++kw) wm[kh][kw] *= d;

  const float g[4] = {0.25f, 0.75f, 0.75f, 0.25f};
  #pragma unroll
  for (int a = 0; a < 6; ++a)
    #pragma unroll
    for (int c = 0; c < 6; ++c) {
      float acc = 0.f;
      #pragma unroll
      for (int dh = 0; dh < 3; ++dh) {
        int u = a - dh;
        if (u < 0 || u > 3) continue;
        #pragma unroll
        for (int dw = 0; dw < 3; ++dw) {
          int v = c - dw;
          if (v < 0 || v > 3) continue;
          acc = fmaf(wm[dh][dw], g[u] * g[v], acc);
        }
      }
      E[a][c] = acc;
    }
}

__device__ inline float style_of(const float* __restrict__ w,
                                 const float* __restrict__ w_dense,
                                 const float* __restrict__ b_mod, int b,
                                 int ic) {
  const float coef_dense = 0.044194173824159216f; // 1/sqrt(512)
  const float* wr = w + b * WD;
  float acc = 0.f;
  for (int k = 0; k < WD; ++k) acc = fmaf(wr[k], w_dense[k * IC + ic], acc);
  return acc * coef_dense + b_mod[ic] + 1.0f;
}

// ---- fused pre-pass: xtp role (bid<2056) + pwfs role (bid>=2056) ----
// xtp: x [b][ic][m][n] f32 -> padded xTg [b][258][258][ic] bf16 (+guard)
// pwfs: PWf frag idx = ph*72 + tap*8 + ocg*4 + ks; 64 lanes x 16B each.
#define XS 268 // u16 LDS stride
__global__ __launch_bounds__(256) void pre_kernel(
    const float* __restrict__ x, const float* __restrict__ w,
    const float* __restrict__ w_dense, const float* __restrict__ b_mod,
    const float* __restrict__ w_conv, __bf16* __restrict__ xTg,
    __bf16* __restrict__ PWf) {
  __shared__ unsigned short buf[64 * XS];
  const int tid = threadIdx.x;
  const int bid = blockIdx.x;

  if (bid >= 2056) {
    // ---- pwfs role: 128 blocks, 4 waves each = one oc per wave ----
    const int bid2 = bid - 2056;
    const int b = bid2 >> 4;
    const int ocq = bid2 & 15;
    const int oc = ocq * 4 + (tid >> 6);
    const int ic = tid & 63;

    float stv = style_of(w, w_dense, b_mod, b, ic);
    float E[6][6];
    compute_E(w_conv, stv, oc, E);

    const int ks = ic >> 4;
    const int h = (ic >> 3) & 1;
    const int e = ic & 7;
    const int lane = (oc & 31) + 32 * h;
    const int ocg = oc >> 5;

    #pragma unroll
    for (int pp = 0; pp < 2; ++pp)
      #pragma unroll
      for (int pq = 0; pq < 2; ++pq) {
        const int ph = pp * 2 + pq;
        #pragma unroll
        for (int j = 0; j < 3; ++j)
          #pragma unroll
          for (int l = 0; l < 3; ++l) {
            const int tap = j * 3 + l;
            float val = E[2 * j + 1 - pp][2 * l + 1 - pq];
            size_t off =
                ((size_t)(((((b * 4 + ph) * 9 + tap) * 2 + ocg) * 4 + ks)) *
                     64 + lane) * 8 + e;
            PWf[off] = (__bf16)val;
          }
      }
    return;
  }

  // ---- xtp role ----
  const int m = bid % 257; // 0..256 ; 256 = guard-zero pass
  const int b = bid / 257;

  if (m == 256) {
    uint4 z = make_uint4(0, 0, 0, 0);
    for (int i = tid; i < 8224; i += 256) {
      int pix = i >> 3;
      int sub = i & 7;
      int pr, pc;
      if (pix < 258) {
        pr = 0; pc = pix;
      } else if (pix < 516) {
        pr = 257; pc = pix - 258;
      } else {
        int rem = pix - 516; // 0..511
        pr = 1 + (rem >> 1);
        pc = (rem & 1) ? 257 : 0;
      }
      *(uint4*)(xTg + ((size_t)(b * PP + pr) * PP + pc) * 64 + sub * 8) = z;
    }
    return;
  }

  const int ln = tid & 63, grp = tid >> 6;
  #pragma unroll
  for (int p = 0; p < 16; ++p) {
    const int ic = p * 4 + grp;
    float4 v = *(const float4*)(x + ((size_t)(b * 64 + ic) * 256 + m) * 256 +
                                ln * 4);
    ushort4 u4;
    u4.x = __builtin_bit_cast(unsigned short, (__bf16)v.x);
    u4.y = __builtin_bit_cast(unsigned short, (__bf16)v.y);
    u4.z = __builtin_bit_cast(unsigned short, (__bf16)v.z);
    u4.w = __builtin_bit_cast(unsigned short, (__bf16)v.w);
    *(ushort4*)&buf[ic * XS + ln * 4] = u4;
  }
  __syncthreads();
  #pragma unroll
  for (int it = 0; it < 8; ++it) {
    int pix = it * 32 + (tid >> 3);
    int g = tid & 7;
    bf16x8 o;
    #pragma unroll
    for (int e = 0; e < 8; ++e)
      o[e] = __builtin_bit_cast(__bf16, buf[(g * 8 + e) * XS + pix]);
    *(bf16x8*)(xTg + ((size_t)(b * PP + m + 1) * PP + (pix + 1)) * 64 +
               g * 8) = o;
  }
}

// ---- small-block streaming MFMA conv: 256 thr, ~4 blocks/CU resident ----
#define CMT 4
#define XR 6  // CMT+2
#define XC 34 // cols (pixels), storage stride

__device__ __forceinline__ void loadA(const bf16x8* __restrict__ Av, int phb,
                                      int ocg, int ks, int l, int lane,
                                      bf16x8 A[3][2]) {
  #pragma unroll
  for (int j = 0; j < 3; ++j) {
    const int tap = j * 3 + l;
    #pragma unroll
    for (int pq = 0; pq < 2; ++pq)
      A[j][pq] =
          Av[(size_t)((((phb + pq) * 9 + tap) * 2 + ocg) * 4 + ks) * 64 + lane];
  }
}

#define GLD_LDS(src, dst)                                                \
  __builtin_amdgcn_global_load_lds(                                      \
      (const __attribute__((address_space(1))) void*)(src),              \
      (__attribute__((address_space(3))) void*)(dst), 16, 0, 0)

// stage one 6x34 tile (rows split across 4 waves) via global_load_lds.
// LDS linear; source granule pre-swizzled: slot s at pixel col holds
// granule s ^ (col&7), matching the reader's XOR.
__device__ __forceinline__ void stage_tile(const __bf16* __restrict__ xTg,
                                           int b, int m0, int n0,
                                           __bf16* xsbuf, int wv, int lane) {
  const int r0 = (XR * wv) >> 2;
  const int r1 = (XR * (wv + 1)) >> 2;
  for (int row = r0; row < r1; ++row) {
    const size_t srow = (size_t)(b * PP + m0 + row) * PP;
    __bf16* ldsrow = xsbuf + row * (XC * 64);
    #pragma unroll
    for (int q = 0; q < 4; ++q) {
      int pix = q * 8 + (lane >> 3);
      int g = (lane & 7) ^ (pix & 7);
      const __bf16* src = xTg + (srow + (n0 + pix)) * 64 + g * 8;
      GLD_LDS(src, ldsrow + q * 512);
    }
    if (lane < 16) {
      int pix = 32 + (lane >> 3);
      int g = (lane & 7) ^ (pix & 7);
      const __bf16* src = xTg + (srow + (n0 + pix)) * 64 + g * 8;
      GLD_LDS(src, ldsrow + 2048);
    }
  }
}

__global__ __launch_bounds__(256, 4) void conv32h_kernel(
    const __bf16* __restrict__ xTg, const __bf16* __restrict__ PWf,
    float* __restrict__ out) {
  __shared__ __bf16 xs[XR * XC * 64]; // 26112 B single buffer

  const int tid = threadIdx.x;
  const int lane = tid & 63;
  const int wv = tid >> 6; // 0..3
  const int pp = wv & 1;
  const int rh = wv >> 1; // 0..1, 2 rows each

  const int bid = blockIdx.x; // 1024 = 8b * 2ocg * 64mtile (raw order)
  const int mtile = bid & 63;
  const int ocg = (bid >> 6) & 1;
  const int b = bid >> 7;
  const int m0 = mtile * CMT;

  const int ln31 = lane & 31;
  const int lh = lane >> 5;
  const bf16x8* Av = (const bf16x8*)PWf;
  const int phb = b * 4 + pp * 2;

  stage_tile(xTg, b, m0, 0, xs, wv, lane);
  __syncthreads();

  #pragma unroll 1
  for (int t = 0; t < 8; ++t) {
    const int n0 = t * 32;

    f32x16 acc[2][2]; // [mw][pq]
    #pragma unroll
    for (int mw = 0; mw < 2; ++mw)
      #pragma unroll
      for (int pq = 0; pq < 2; ++pq)
        #pragma unroll
        for (int e = 0; e < 16; ++e) acc[mw][pq][e] = 0.f;

    int ks = 0, l = 0;
    #pragma unroll 1
    for (int it = 0; it < 12; ++it) {
      bf16x8 Ac[3][2];
      loadA(Av, phb, ocg, ks, l, lane, Ac);

      bf16x8 Bf[4];
      const int col_t = ln31 + l;
      const int gneed = ks * 2 + lh;
      #pragma unroll
      for (int r = 0; r < 4; ++r) {
        const int lds_row = 2 * rh + r;
        Bf[r] = *(const bf16x8*)(xs + ((lds_row * XC + col_t) * 8 +
                                       (gneed ^ (col_t & 7))) * 8);
      }

      __builtin_amdgcn_s_setprio(1);
      #pragma unroll
      for (int r = 0; r < 4; ++r) {
        #pragma unroll
        for (int j = 0; j < 3; ++j) {
          const int mw = r - j;
          if (mw == 0 || mw == 1) {
            acc[mw][0] = __builtin_amdgcn_mfma_f32_32x32x16_bf16(
                Ac[j][0], Bf[r], acc[mw][0], 0, 0, 0);
            acc[mw][1] = __builtin_amdgcn_mfma_f32_32x32x16_bf16(
                Ac[j][1], Bf[r], acc[mw][1], 0, 0, 0);
          }
        }
      }
      __builtin_amdgcn_s_setprio(0);

      l = (l == 2) ? 0 : l + 1;
      ks = (l == 0) ? (ks + 1) & 3 : ks;
    }

    // epilogue: interleave pq in-register -> coalesced nontemporal stores
    #pragma unroll
    for (int mw = 0; mw < 2; ++mw) {
      const int p = 2 * (m0 + 2 * rh + mw) + pp;
      #pragma unroll
      for (int rr = 0; rr < 16; ++rr) {
        const int oc_loc = (rr & 3) + 8 * (rr >> 2) + 4 * lh;
        const int oc = ocg * 32 + oc_loc;
        size_t off =
            ((size_t)(b * 64 + oc) * 512 + p) * 512 + 2 * n0 + 2 * ln31;
        f32x2 v2;
        v2[0] = acc[mw][0][rr];
        v2[1] = acc[mw][1][rr];
        __builtin_nontemporal_store(v2, (f32x2*)(out + off));
      }
    }

    if (t < 7) {
      __syncthreads(); // LDS consumed by all waves -> safe to overwrite
      stage_tile(xTg, b, m0, n0 + 32, xs, wv, lane);
      __syncthreads(); // stage complete (implicit vmcnt drain)
    }
  }
}

// ===================== fallback: f32 path =====================
__global__ __launch_bounds__(64) void pw_kernel(
    const float* __restrict__ w, const float* __restrict__ w_dense,
    const float* __restrict__ b_mod, const float* __restrict__ w_conv,
    float* __restrict__ PW) {
  const int oc = blockIdx.x;
  const int b = blockIdx.y;
  const int ic = threadIdx.x;
  float stv = style_of(w, w_dense, b_mod, b, ic);
  float E[6][6];
  compute_E(w_conv, stv, oc, E);
  #pragma unroll
  for (int pp = 0; pp < 2; ++pp)
    #pragma unroll
    for (int pq = 0; pq < 2; ++pq)
      #pragma unroll
      for (int j = 0; j < 3; ++j)
        #pragma unroll
        for (int l = 0; l < 3; ++l)
          PW[(((size_t)((b * 4 + pp * 2 + pq) * OC + oc) * IC + ic) * 9) +
             j * 3 + l] = E[2 * j + 1 - pp][2 * l + 1 - pq];
}

#define MT 16
#define NT 64
#define ICC 8
#define XROWS 18
#define XCOLS 66
#define XSTRIDE 68

__global__ __launch_bounds__(256) void conv_kernel(
    const float* __restrict__ x, const float* __restrict__ PW,
    float* __restrict__ out) {
  __shared__ float lds_x[ICC][XROWS][XSTRIDE];
  __shared__ float lds_w[4][ICC][9][4];

  const int tid = threadIdx.x;
  const int tn = tid & 15;
  const int tm = tid >> 4;
  const int bx = blockIdx.x;
  const int ntile = bx & 3;
  const int mtile = bx >> 2;
  const int ocg = blockIdx.y;
  const int b = blockIdx.z;
  const int m0 = mtile * MT;
  const int n0 = ntile * NT;

  float acc[4][4][4];
  #pragma unroll
  for (int o = 0; o < 4; ++o)
    #pragma unroll
    for (int ph = 0; ph < 4; ++ph)
      #pragma unroll
      for (int s = 0; s < 4; ++s) acc[o][ph][s] = 0.f;

  for (int ic0 = 0; ic0 < IC; ic0 += ICC) {
    __syncthreads();
    for (int ici = 0; ici < ICC; ++ici) {
      const float* xsrc = x + (size_t)(b * IC + ic0 + ici) * HH * HH;
      for (int rc = tid; rc < XROWS * XCOLS; rc += 256) {
        int r = rc / XCOLS;
        int c = rc - r * XCOLS;
        int gr = m0 - 1 + r;
        int gc = n0 - 1 + c;
        float v = 0.f;
        if ((unsigned)gr < HH && (unsigned)gc < HH) v = xsrc[gr * HH + gc];
        lds_x[ici][r][c] = v;
      }
    }
    for (int idx = tid; idx < 4 * ICC * 9 * 4; idx += 256) {
      int o = idx / (ICC * 9 * 4);
      int rem = idx - o * (ICC * 9 * 4);
      int ici = rem / 36;
      int r2 = rem - ici * 36;
      int t = r2 >> 2;
      int ph = r2 & 3;
      lds_w[o][ici][t][ph] =
          PW[(((size_t)((b * 4 + ph) * OC + (ocg * 4 + o)) * IC +
               (ic0 + ici)) * 9) + t];
    }
    __syncthreads();
    for (int ici = 0; ici < ICC; ++ici) {
      #pragma unroll
      for (int j = 0; j < 3; ++j) {
        const float* xr = &lds_x[ici][tm + j][tn * 4];
        float4 a4 = *(const float4*)xr;
        float2 a2 = *(const float2*)(xr + 4);
        float xv[6] = {a4.x, a4.y, a4.z, a4.w, a2.x, a2.y};
        #pragma unroll
        for (int l = 0; l < 3; ++l) {
          #pragma unroll
          for (int o = 0; o < 4; ++o) {
            float4 wv = *(const float4*)&lds_w[o][ici][j * 3 + l][0];
            #pragma unroll
            for (int s = 0; s < 4; ++s) {
              acc[o][0][s] = fmaf(wv.x, xv[l + s], acc[o][0][s]);
              acc[o][1][s] = fmaf(wv.y, xv[l + s], acc[o][1][s]);
              acc[o][2][s] = fmaf(wv.z, xv[l + s], acc[o][2][s]);
              acc[o][3][s] = fmaf(wv.w, xv[l + s], acc[o][3][s]);
            }
          }
        }
      }
    }
  }

  #pragma unroll
  for (int o = 0; o < 4; ++o) {
    #pragma unroll
    for (int pp = 0; pp < 2; ++pp) {
      const int p = 2 * (m0 + tm) + pp;
      float* dst = out +
          (((size_t)(b * OC + ocg * 4 + o) * 512 + p) * 512) + 2 * n0 + 8 * tn;
      float4 v0 = make_float4(acc[o][pp * 2 + 0][0], acc[o][pp * 2 + 1][0],
                              acc[o][pp * 2 + 0][1], acc[o][pp * 2 + 1][1]);
      float4 v1 = make_float4(acc[o][pp * 2 + 0][2], acc[o][pp * 2 + 1][2],
                              acc[o][pp * 2 + 0][3], acc[o][pp * 2 + 1][3]);
      *(float4*)dst = v0;
      *(float4*)(dst + 4) = v1;
    }
  }
}

extern "C" void kernel_launch(void* const* d_in, const int* in_sizes, int n_in,
                              void* d_out, int out_size, void* d_ws,
                              size_t ws_size, hipStream_t stream) {
  const float* x = (const float*)d_in[0];
  const float* w = (const float*)d_in[1];
  const float* w_conv = (const float*)d_in[2];
  const float* w_dense = (const float*)d_in[3];
  const float* b_mod = (const float*)d_in[4];
  float* out = (float*)d_out;

  const size_t PWF_BYTES = (size_t)8 * 4 * 9 * 2 * 4 * 64 * 8 * 2; // 2359296
  const size_t XTG_BYTES = (size_t)8 * PP * PP * 64 * 2;           // 68161536
  const size_t NEED_NEW = PWF_BYTES + XTG_BYTES;

  if (ws_size >= NEED_NEW) {
    __bf16* PWf = (__bf16*)d_ws;
    __bf16* xTg = (__bf16*)((char*)d_ws + PWF_BYTES);
    pre_kernel<<<dim3(2056 + 128), 256, 0, stream>>>(x, w, w_dense, b_mod,
                                                     w_conv, xTg, PWf);
    conv32h_kernel<<<dim3(1024), 256, 0, stream>>>(xTg, PWf, out);
  } else {
    float* PW = (float*)d_ws;
    pw_kernel<<<dim3(OC, NB), 64, 0, stream>>>(w, w_dense, b_mod, w_conv, PW);
    conv_kernel<<<dim3(64, 16, NB), 256, 0, stream>>>(x, PW, out);
  }
}